// Round 2
// baseline (154.916 us; speedup 1.0000x reference)
//
#include <hip/hip_runtime.h>
#include <hip/hip_bf16.h>
#include <cstdint>
#include <cstddef>

#define B_ 2
#define N_ 2048
#define D_ 256
#define H_ 8
#define HID_ 64
#define EN_ 2
#define ALPHA 0.2f
#define NEG (-9000000000000000.0f)

typedef __bf16 bf16x8 __attribute__((ext_vector_type(8)));
typedef float f32x4 __attribute__((ext_vector_type(4)));
typedef unsigned short ushort8 __attribute__((ext_vector_type(8)));
typedef float float4v __attribute__((ext_vector_type(4)));
typedef float float2v __attribute__((ext_vector_type(2)));

__device__ __forceinline__ float bf2f(unsigned short u) {
    unsigned int x = ((unsigned int)u) << 16;
    return __builtin_bit_cast(float, x);
}
__device__ __forceinline__ unsigned short f2bf(float f) {
    unsigned int u = __builtin_bit_cast(unsigned int, f);
    unsigned int r = u + 0x7FFFu + ((u >> 16) & 1u);  // RNE
    return (unsigned short)(r >> 16);
}
__device__ __forceinline__ float leakyf(float x) { return x >= 0.f ? x : ALPHA * x; }

// load 8 consecutive f32, convert to 8 bf16
__device__ __forceinline__ ushort8 cvt8(const float* __restrict__ p) {
    float4v x0 = *(const float4v*)p;
    float4v x1 = *(const float4v*)(p + 4);
    ushort8 r;
    #pragma unroll
    for (int e = 0; e < 4; ++e) { r[e] = f2bf(x0[e]); r[e + 4] = f2bf(x1[e]); }
    return r;
}

// ---------- K0: transpose W_att[h][d][o] f32 -> WT[h][o][d] bf16 (tiny) ----------
__global__ void k_transpose_w(const float* __restrict__ W,
                              unsigned short* __restrict__ WT) {
    int h = blockIdx.x;
    const float* Wh = W + (size_t)h * D_ * HID_;
    unsigned short* WTh = WT + (size_t)h * HID_ * D_;
    for (int idx = threadIdx.x; idx < D_ * HID_; idx += blockDim.x) {
        int d = idx / HID_, o = idx % HID_;
        WTh[o * D_ + d] = f2bf(Wh[idx]);
    }
}

// ---------- K1: wh = fea @ W_att (per b,h), fused e1/e2, write whT bf16 ----------
// block: 256 thr (4 waves), tile 64 rows x 64 cols, K=256 in 4 steps of 64.
__global__ __launch_bounds__(256) void k_wh(
    const float* __restrict__ fea,            // [B][N][D] f32
    const unsigned short* __restrict__ WT,    // [H][64][256] bf16
    const float* __restrict__ a_att,          // [H][128] f32
    unsigned short* __restrict__ whT,         // [B][H][64][N] bf16
    float* __restrict__ e1, float* __restrict__ e2)
{
    int bid = blockIdx.x;
    int i0 = (bid & 31) << 6;
    int h  = (bid >> 5) & 7;
    int b  = bid >> 8;

    __shared__ __align__(16) union SmemA {
        struct { unsigned short fa[64 * 72]; unsigned short wt[64 * 72]; } s;
        float tr[64 * 65];
    } u;

    int t = threadIdx.x;
    int lane = t & 63;
    int wv = t >> 6;          // wave id 0..3
    int r = lane & 15, q = lane >> 4;
    int ra = t >> 2;          // staging row 0..63
    int cc = (t & 3) * 16;    // staging col chunk

    f32x4 acc[4] = {};

    const float* fearow = fea + ((size_t)(b * N_ + i0 + ra)) * D_;
    const unsigned short* wtrow = WT + ((size_t)(h * 64 + ra)) * D_;

    for (int d0 = 0; d0 < D_; d0 += 64) {
        *(ushort8*)&u.s.fa[ra * 72 + cc]     = cvt8(fearow + d0 + cc);
        *(ushort8*)&u.s.fa[ra * 72 + cc + 8] = cvt8(fearow + d0 + cc + 8);
        *(ushort8*)&u.s.wt[ra * 72 + cc]     = *(const ushort8*)(wtrow + d0 + cc);
        *(ushort8*)&u.s.wt[ra * 72 + cc + 8] = *(const ushort8*)(wtrow + d0 + cc + 8);
        __syncthreads();
        #pragma unroll
        for (int k0 = 0; k0 < 64; k0 += 32) {
            bf16x8 a = *(const bf16x8*)&u.s.fa[(16 * wv + r) * 72 + k0 + q * 8];
            #pragma unroll
            for (int f = 0; f < 4; ++f) {
                bf16x8 bb = *(const bf16x8*)&u.s.wt[(16 * f + r) * 72 + k0 + q * 8];
                acc[f] = __builtin_amdgcn_mfma_f32_16x16x32_bf16(a, bb, acc[f], 0, 0, 0);
            }
        }
        __syncthreads();
    }

    // e1/e2 epilogue: e1[i] = sum_o wh[i][o]*a1[o]
    float a1v[4], a2v[4];
    #pragma unroll
    for (int f = 0; f < 4; ++f) {
        a1v[f] = a_att[h * 128 + 16 * f + r];
        a2v[f] = a_att[h * 128 + 64 + 16 * f + r];
    }
    #pragma unroll
    for (int rr = 0; rr < 4; ++rr) {
        float s1 = 0.f, s2 = 0.f;
        #pragma unroll
        for (int f = 0; f < 4; ++f) { s1 += acc[f][rr] * a1v[f]; s2 += acc[f][rr] * a2v[f]; }
        #pragma unroll
        for (int m = 1; m < 16; m <<= 1) {
            s1 += __shfl_xor(s1, m, 64);
            s2 += __shfl_xor(s2, m, 64);
        }
        if (r == 0) {
            int i = i0 + 16 * wv + 4 * q + rr;
            size_t idx = ((size_t)(b * H_ + h)) * N_ + i;
            e1[idx] = s1; e2[idx] = s2;
        }
    }

    // transpose wh tile -> whT (via LDS)
    #pragma unroll
    for (int f = 0; f < 4; ++f)
        #pragma unroll
        for (int rr = 0; rr < 4; ++rr)
            u.tr[(16 * f + r) * 65 + 16 * wv + 4 * q + rr] = acc[f][rr];
    __syncthreads();
    {
        int o = t >> 2;
        int ch = (t & 3) * 16;
        unsigned short tmp[16];
        #pragma unroll
        for (int e = 0; e < 16; ++e) tmp[e] = f2bf(u.tr[o * 65 + ch + e]);
        ushort8* dst = (ushort8*)(whT + (((size_t)(b * H_ + h) * 64 + o)) * N_ + i0 + ch);
        dst[0] = *(ushort8*)&tmp[0];
        dst[1] = *(ushort8*)&tmp[8];
    }
}

// ---------- K2: per-row softmax stats (m, Z) for stage 1 ----------
__global__ __launch_bounds__(256) void k_stats1(
    const float* __restrict__ adj,
    const float* __restrict__ e1, const float* __restrict__ e2,
    float* __restrict__ m1, float* __restrict__ z1)
{
    int idx = blockIdx.x * 4 + (threadIdx.x >> 6);  // (b*H+h)*N + i
    int lane = threadIdx.x & 63;
    int i = idx & (N_ - 1);
    int h = (idx >> 11) & 7;
    int b = idx >> 14;
    float eRow = e1[idx];
    const float* arow = adj + ((size_t)(b * N_ + i)) * N_;
    const float* e2row = e2 + ((size_t)(b * H_ + h)) * N_;
    float m = -INFINITY, Z = 0.f;
    for (int it = 0; it < N_ / 64; ++it) {
        int j = it * 64 + lane;
        float a = arow[j];
        float e = leakyf(eRow + e2row[j]);
        float tv = (a != 0.f) ? e * a : 0.f;
        if (tv == 0.f) tv = NEG;
        float nm = fmaxf(m, tv);
        Z = Z * __expf(m - nm) + __expf(tv - nm);
        m = nm;
    }
    #pragma unroll
    for (int s = 1; s < 64; s <<= 1) {
        float mo = __shfl_xor(m, s, 64);
        float Zo = __shfl_xor(Z, s, 64);
        float nm = fmaxf(m, mo);
        Z = Z * __expf(m - nm) + Zo * __expf(mo - nm);
        m = nm;
    }
    if (lane == 0) { m1[idx] = m; z1[idx] = Z; }
}

// ---------- K3: x = elu(P @ wh), P generated on the fly, MFMA ----------
__global__ __launch_bounds__(256) void k_pv1(
    const float* __restrict__ adj,
    const unsigned short* __restrict__ whT,   // [B][H][64][N] bf16
    const float* __restrict__ e1, const float* __restrict__ e2,
    const float* __restrict__ m1, const float* __restrict__ z1,
    float* __restrict__ x_t)                  // [B][N][512] f32
{
    int bid = blockIdx.x;
    int i0 = (bid & 31) << 6;
    int h  = (bid >> 5) & 7;
    int b  = bid >> 8;

    __shared__ __align__(16) unsigned short p_lds[64 * 72];
    __shared__ __align__(16) unsigned short wt_lds[64 * 72];

    int t = threadIdx.x;
    int lane = t & 63;
    int wv = t >> 6;
    int r = lane & 15, q = lane >> 4;
    int ra = t >> 2;
    int cc = (t & 3) * 16;

    size_t rowIdx = ((size_t)(b * H_ + h)) * N_ + i0 + ra;
    float eRow = e1[rowIdx];
    float mRow = m1[rowIdx];
    float zInv = 1.f / z1[rowIdx];
    const float* e2row = e2 + ((size_t)(b * H_ + h)) * N_;
    const float* arow = adj + ((size_t)(b * N_ + i0 + ra)) * N_;
    const unsigned short* wrow = whT + (((size_t)(b * H_ + h)) * 64 + ra) * N_;

    f32x4 acc[4] = {};

    for (int j0 = 0; j0 < N_; j0 += 64) {
        // P chunk: row ra, 16 cols
        float4v av[4], ev[4];
        #pragma unroll
        for (int u4 = 0; u4 < 4; ++u4) {
            av[u4] = *(const float4v*)(arow + j0 + cc + u4 * 4);
            ev[u4] = *(const float4v*)(e2row + j0 + cc + u4 * 4);
        }
        unsigned short pv[16];
        #pragma unroll
        for (int e = 0; e < 16; ++e) {
            float a = av[e >> 2][e & 3];
            float x = leakyf(eRow + ev[e >> 2][e & 3]);
            float tv = (a != 0.f) ? x * a : 0.f;
            if (tv == 0.f) tv = NEG;
            pv[e] = f2bf(__expf(tv - mRow) * zInv);
        }
        *(ushort8*)&p_lds[ra * 72 + cc]     = *(ushort8*)&pv[0];
        *(ushort8*)&p_lds[ra * 72 + cc + 8] = *(ushort8*)&pv[8];
        // stage whT tile
        *(ushort8*)&wt_lds[ra * 72 + cc]     = *(const ushort8*)(wrow + j0 + cc);
        *(ushort8*)&wt_lds[ra * 72 + cc + 8] = *(const ushort8*)(wrow + j0 + cc + 8);
        __syncthreads();
        #pragma unroll
        for (int k0 = 0; k0 < 64; k0 += 32) {
            bf16x8 a = *(const bf16x8*)&p_lds[(16 * wv + r) * 72 + k0 + q * 8];
            #pragma unroll
            for (int f = 0; f < 4; ++f) {
                bf16x8 bb = *(const bf16x8*)&wt_lds[(16 * f + r) * 72 + k0 + q * 8];
                acc[f] = __builtin_amdgcn_mfma_f32_16x16x32_bf16(a, bb, acc[f], 0, 0, 0);
            }
        }
        __syncthreads();
    }

    // epilogue: elu + write x_t[b][i][h*64 + o] f32
    #pragma unroll
    for (int f = 0; f < 4; ++f) {
        #pragma unroll
        for (int rr = 0; rr < 4; ++rr) {
            float v = acc[f][rr];
            v = v > 0.f ? v : expm1f(v);
            int i = i0 + 16 * wv + 4 * q + rr;
            x_t[((size_t)(b * N_ + i)) * (H_ * HID_) + h * 64 + 16 * f + r] = v;
        }
    }
}

// ---------- K4: wh2 = x @ W_last (512x2), fused g1/g2 ----------
__global__ __launch_bounds__(256) void k_wh2(
    const float* __restrict__ x_t,
    const float* __restrict__ W_last,  // [512][2] f32
    const float* __restrict__ a_last,  // [4] f32
    float* __restrict__ wh2, float* __restrict__ g1, float* __restrict__ g2)
{
    int idx = blockIdx.x * 4 + (threadIdx.x >> 6);  // b*N + n
    int lane = threadIdx.x & 63;
    const float* xrow = x_t + (size_t)idx * 512;
    float a0 = 0.f, a1 = 0.f;
    #pragma unroll
    for (int it = 0; it < 8; ++it) {
        int k = it * 64 + lane;
        float xv = xrow[k];
        float2v wl = *(const float2v*)(W_last + k * 2);
        a0 += xv * wl[0];
        a1 += xv * wl[1];
    }
    #pragma unroll
    for (int s = 1; s < 64; s <<= 1) {
        a0 += __shfl_xor(a0, s, 64);
        a1 += __shfl_xor(a1, s, 64);
    }
    if (lane == 0) {
        wh2[idx * 2] = a0; wh2[idx * 2 + 1] = a1;
        g1[idx] = a0 * a_last[0] + a1 * a_last[1];
        g2[idx] = a0 * a_last[2] + a1 * a_last[3];
    }
}

// ---------- K5: final attention + elu, online flash per row ----------
__global__ __launch_bounds__(256) void k_out(
    const float* __restrict__ adj,
    const float* __restrict__ wh2,
    const float* __restrict__ g1, const float* __restrict__ g2,
    float* __restrict__ out)
{
    int idx = blockIdx.x * 4 + (threadIdx.x >> 6); // b*N + i
    int lane = threadIdx.x & 63;
    int b = idx >> 11;
    float gi = g1[idx];
    const float* arow = adj + (size_t)idx * N_;
    const float* g2b = g2 + (size_t)b * N_;
    const float* wh2b = wh2 + (size_t)b * N_ * 2;
    float m = -INFINITY, Z = 0.f, acc0 = 0.f, acc1 = 0.f;
    for (int it = 0; it < N_ / 64; ++it) {
        int j = it * 64 + lane;
        float a = arow[j];
        float e = leakyf(gi + g2b[j]);
        float tv = (a != 0.f) ? e * a : 0.f;
        if (tv == 0.f) tv = NEG;
        float nm = fmaxf(m, tv);
        float sc = __expf(m - nm);
        float p = __expf(tv - nm);
        m = nm;
        float2v wv2 = *(const float2v*)(wh2b + 2 * j);
        Z = Z * sc + p;
        acc0 = acc0 * sc + p * wv2[0];
        acc1 = acc1 * sc + p * wv2[1];
    }
    #pragma unroll
    for (int s = 1; s < 64; s <<= 1) {
        float mo = __shfl_xor(m, s, 64), Zo = __shfl_xor(Z, s, 64);
        float b0 = __shfl_xor(acc0, s, 64), b1 = __shfl_xor(acc1, s, 64);
        float nm = fmaxf(m, mo);
        float s1 = __expf(m - nm), s2 = __expf(mo - nm);
        m = nm;
        Z = Z * s1 + Zo * s2;
        acc0 = acc0 * s1 + b0 * s2;
        acc1 = acc1 * s1 + b1 * s2;
    }
    if (lane == 0) {
        float o0 = acc0 / Z, o1 = acc1 / Z;
        o0 = o0 > 0.f ? o0 : expm1f(o0);
        o1 = o1 > 0.f ? o1 : expm1f(o1);
        float2v ov; ov[0] = o0; ov[1] = o1;
        *(float2v*)(out + idx * 2) = ov;
    }
}

extern "C" void kernel_launch(void* const* d_in, const int* in_sizes, int n_in,
                              void* d_out, int out_size, void* d_ws, size_t ws_size,
                              hipStream_t stream) {
    const float* fea    = (const float*)d_in[0];
    const float* adj    = (const float*)d_in[1];
    const float* W_att  = (const float*)d_in[2];
    const float* a_att  = (const float*)d_in[3];
    const float* W_last = (const float*)d_in[4];
    const float* a_last = (const float*)d_in[5];

    char* ws = (char*)d_ws;
    // layout (bytes)
    unsigned short* whT = (unsigned short*)(ws + 0);          // 4,194,304
    float* x_t = (float*)(ws + 4194304);                      // 8,388,608
    float* e1  = (float*)(ws + 12582912);                     // 131,072
    float* e2  = (float*)(ws + 12713984);                     // 131,072
    float* m1  = (float*)(ws + 12845056);                     // 131,072
    float* z1  = (float*)(ws + 12976128);                     // 131,072
    float* wh2 = (float*)(ws + 13107200);                     // 32,768
    float* g1  = (float*)(ws + 13139968);                     // 16,384
    float* g2  = (float*)(ws + 13156352);                     // 16,384
    unsigned short* WT = (unsigned short*)(ws + 13172736);    // 262,144

    hipLaunchKernelGGL(k_transpose_w, dim3(H_), dim3(256), 0, stream, W_att, WT);
    hipLaunchKernelGGL(k_wh, dim3(B_ * H_ * (N_ / 64)), dim3(256), 0, stream,
                       fea, WT, a_att, whT, e1, e2);
    hipLaunchKernelGGL(k_stats1, dim3(B_ * H_ * N_ / 4), dim3(256), 0, stream,
                       adj, e1, e2, m1, z1);
    hipLaunchKernelGGL(k_pv1, dim3(B_ * H_ * (N_ / 64)), dim3(256), 0, stream,
                       adj, whT, e1, e2, m1, z1, x_t);
    hipLaunchKernelGGL(k_wh2, dim3(B_ * N_ / 4), dim3(256), 0, stream,
                       x_t, W_last, a_last, wh2, g1, g2);
    hipLaunchKernelGGL(k_out, dim3(B_ * N_ / 4), dim3(256), 0, stream,
                       adj, wh2, g1, g2, (float*)d_out);
}

// Round 3
// 122.231 us; speedup vs baseline: 1.2674x; 1.2674x over previous
//
#include <hip/hip_runtime.h>
#include <hip/hip_bf16.h>
#include <cstdint>
#include <cstddef>

#define B_ 2
#define N_ 2048
#define D_ 256
#define H_ 8
#define HID_ 64
#define EN_ 2
#define ALPHA 0.2f
#define NEGBIG (-3.0e38f)

typedef __bf16 bf16x8 __attribute__((ext_vector_type(8)));
typedef float f32x4 __attribute__((ext_vector_type(4)));
typedef unsigned short ushort8 __attribute__((ext_vector_type(8)));
typedef float float4v __attribute__((ext_vector_type(4)));
typedef float float2v __attribute__((ext_vector_type(2)));

__device__ __forceinline__ unsigned short f2bf(float f) {
    unsigned int u = __builtin_bit_cast(unsigned int, f);
    unsigned int r = u + 0x7FFFu + ((u >> 16) & 1u);  // RNE
    return (unsigned short)(r >> 16);
}
__device__ __forceinline__ float leakyf(float x) { return fmaxf(x, ALPHA * x); }

// load 8 consecutive f32, convert to 8 bf16
__device__ __forceinline__ ushort8 cvt8(const float* __restrict__ p) {
    float4v x0 = *(const float4v*)p;
    float4v x1 = *(const float4v*)(p + 4);
    ushort8 r;
    #pragma unroll
    for (int e = 0; e < 4; ++e) { r[e] = f2bf(x0[e]); r[e + 4] = f2bf(x1[e]); }
    return r;
}

// ---------- K0: transpose W_att[h][d][o] f32 -> WT[h][o][d] bf16 (tiny) ----------
__global__ void k_transpose_w(const float* __restrict__ W,
                              unsigned short* __restrict__ WT) {
    int h = blockIdx.x;
    const float* Wh = W + (size_t)h * D_ * HID_;
    unsigned short* WTh = WT + (size_t)h * HID_ * D_;
    for (int idx = threadIdx.x; idx < D_ * HID_; idx += blockDim.x) {
        int d = idx / HID_, o = idx % HID_;
        WTh[o * D_ + d] = f2bf(Wh[idx]);
    }
}

// ---------- K1: wh = fea @ W_att (per b,h), fused e1/e2, write whT bf16 ----------
__global__ __launch_bounds__(256) void k_wh(
    const float* __restrict__ fea,            // [B][N][D] f32
    const unsigned short* __restrict__ WT,    // [H][64][256] bf16
    const float* __restrict__ a_att,          // [H][128] f32
    unsigned short* __restrict__ whT,         // [B][H][64][N] bf16
    float* __restrict__ e1, float* __restrict__ e2)
{
    int bid = blockIdx.x;
    int i0 = (bid & 31) << 6;
    int h  = (bid >> 5) & 7;
    int b  = bid >> 8;

    __shared__ __align__(16) union SmemA {
        struct { unsigned short fa[64 * 72]; unsigned short wt[64 * 72]; } s;
        float tr[64 * 65];
    } u;

    int t = threadIdx.x;
    int lane = t & 63;
    int wv = t >> 6;          // wave id 0..3
    int r = lane & 15, q = lane >> 4;
    int ra = t >> 2;          // staging row 0..63
    int cc = (t & 3) * 16;    // staging col chunk

    f32x4 acc[4] = {};

    const float* fearow = fea + ((size_t)(b * N_ + i0 + ra)) * D_;
    const unsigned short* wtrow = WT + ((size_t)(h * 64 + ra)) * D_;

    for (int d0 = 0; d0 < D_; d0 += 64) {
        *(ushort8*)&u.s.fa[ra * 72 + cc]     = cvt8(fearow + d0 + cc);
        *(ushort8*)&u.s.fa[ra * 72 + cc + 8] = cvt8(fearow + d0 + cc + 8);
        *(ushort8*)&u.s.wt[ra * 72 + cc]     = *(const ushort8*)(wtrow + d0 + cc);
        *(ushort8*)&u.s.wt[ra * 72 + cc + 8] = *(const ushort8*)(wtrow + d0 + cc + 8);
        __syncthreads();
        #pragma unroll
        for (int k0 = 0; k0 < 64; k0 += 32) {
            bf16x8 a = *(const bf16x8*)&u.s.fa[(16 * wv + r) * 72 + k0 + q * 8];
            #pragma unroll
            for (int f = 0; f < 4; ++f) {
                bf16x8 bb = *(const bf16x8*)&u.s.wt[(16 * f + r) * 72 + k0 + q * 8];
                acc[f] = __builtin_amdgcn_mfma_f32_16x16x32_bf16(a, bb, acc[f], 0, 0, 0);
            }
        }
        __syncthreads();
    }

    // e1/e2 epilogue
    float a1v[4], a2v[4];
    #pragma unroll
    for (int f = 0; f < 4; ++f) {
        a1v[f] = a_att[h * 128 + 16 * f + r];
        a2v[f] = a_att[h * 128 + 64 + 16 * f + r];
    }
    #pragma unroll
    for (int rr = 0; rr < 4; ++rr) {
        float s1 = 0.f, s2 = 0.f;
        #pragma unroll
        for (int f = 0; f < 4; ++f) { s1 += acc[f][rr] * a1v[f]; s2 += acc[f][rr] * a2v[f]; }
        #pragma unroll
        for (int m = 1; m < 16; m <<= 1) {
            s1 += __shfl_xor(s1, m, 64);
            s2 += __shfl_xor(s2, m, 64);
        }
        if (r == 0) {
            int i = i0 + 16 * wv + 4 * q + rr;
            size_t idx = ((size_t)(b * H_ + h)) * N_ + i;
            e1[idx] = s1; e2[idx] = s2;
        }
    }

    // transpose wh tile -> whT (via LDS)
    #pragma unroll
    for (int f = 0; f < 4; ++f)
        #pragma unroll
        for (int rr = 0; rr < 4; ++rr)
            u.tr[(16 * f + r) * 65 + 16 * wv + 4 * q + rr] = acc[f][rr];
    __syncthreads();
    {
        int o = t >> 2;
        int ch = (t & 3) * 16;
        unsigned short tmp[16];
        #pragma unroll
        for (int e = 0; e < 16; ++e) tmp[e] = f2bf(u.tr[o * 65 + ch + e]);
        ushort8* dst = (ushort8*)(whT + (((size_t)(b * H_ + h) * 64 + o)) * N_ + i0 + ch);
        dst[0] = *(ushort8*)&tmp[0];
        dst[1] = *(ushort8*)&tmp[8];
    }
}

// ---------- K2: per-row softmax stats (m, Z), single pass, register-resident ----------
__global__ __launch_bounds__(256) void k_stats1(
    const float* __restrict__ adj,
    const float* __restrict__ e1, const float* __restrict__ e2,
    float* __restrict__ m1, float* __restrict__ z1)
{
    int idx = blockIdx.x * 4 + (threadIdx.x >> 6);  // (b*H+h)*N + i
    int lane = threadIdx.x & 63;
    int i = idx & (N_ - 1);
    int h = (idx >> 11) & 7;
    int b = idx >> 14;
    float eRow = e1[idx];
    const float* arow = adj + ((size_t)(b * N_ + i)) * N_;
    const float* e2row = e2 + ((size_t)(b * H_ + h)) * N_;

    float ep[32];
    float M = NEGBIG;
    #pragma unroll
    for (int it = 0; it < 8; ++it) {
        int j = it * 256 + lane * 4;
        float4v a4 = *(const float4v*)(arow + j);
        float4v s4 = *(const float4v*)(e2row + j);
        #pragma unroll
        for (int e = 0; e < 4; ++e) {
            float l = leakyf(eRow + s4[e]);
            float v = (a4[e] != 0.f) ? l : NEGBIG;
            ep[it * 4 + e] = v;
            M = fmaxf(M, v);
        }
    }
    #pragma unroll
    for (int s = 1; s < 64; s <<= 1) M = fmaxf(M, __shfl_xor(M, s, 64));
    float Z = 0.f;
    #pragma unroll
    for (int k = 0; k < 32; ++k) Z += __expf(ep[k] - M);
    #pragma unroll
    for (int s = 1; s < 64; s <<= 1) Z += __shfl_xor(Z, s, 64);
    if (lane == 0) { m1[idx] = M; z1[idx] = Z; }
}

// ---------- K3: x_part[s] = P_chunk @ wh (raw, pre-elu, un-normalized) ----------
__global__ __launch_bounds__(256) void k_pv1(
    const float* __restrict__ adj,
    const unsigned short* __restrict__ whT,   // [B][H][64][N] bf16
    const float* __restrict__ e1, const float* __restrict__ e2,
    const float* __restrict__ m1,
    float* __restrict__ x_part, int jPer)     // [S][B][N][512] f32
{
    int s  = blockIdx.x;
    int i0 = blockIdx.y << 6;
    int bh = blockIdx.z;                      // b*H + h
    int h = bh & 7, b = bh >> 3;
    int jBeg = s * jPer;

    __shared__ __align__(16) unsigned short p_lds[64 * 72];
    __shared__ __align__(16) unsigned short wt_lds[64 * 72];

    int t = threadIdx.x;
    int lane = t & 63;
    int wv = t >> 6;
    int r = lane & 15, q = lane >> 4;
    int ra = t >> 2;
    int cc = (t & 3) * 16;

    size_t rowIdx = ((size_t)bh) * N_ + i0 + ra;
    float eRow = e1[rowIdx];
    float mRow = m1[rowIdx];
    const float* e2row = e2 + ((size_t)bh) * N_;
    const float* arow = adj + ((size_t)(b * N_ + i0 + ra)) * N_;
    const unsigned short* wrow = whT + (((size_t)bh) * 64 + ra) * N_;

    f32x4 acc[4] = {};

    for (int j0 = jBeg; j0 < jBeg + jPer; j0 += 64) {
        float4v av[4], ev[4];
        #pragma unroll
        for (int u4 = 0; u4 < 4; ++u4) {
            av[u4] = *(const float4v*)(arow + j0 + cc + u4 * 4);
            ev[u4] = *(const float4v*)(e2row + j0 + cc + u4 * 4);
        }
        unsigned short pv[16];
        #pragma unroll
        for (int e = 0; e < 16; ++e) {
            float l = leakyf(eRow + ev[e >> 2][e & 3]) - mRow;
            float p = (av[e >> 2][e & 3] != 0.f) ? __expf(l) : 0.f;
            pv[e] = f2bf(p);
        }
        *(ushort8*)&p_lds[ra * 72 + cc]     = *(ushort8*)&pv[0];
        *(ushort8*)&p_lds[ra * 72 + cc + 8] = *(ushort8*)&pv[8];
        *(ushort8*)&wt_lds[ra * 72 + cc]     = *(const ushort8*)(wrow + j0 + cc);
        *(ushort8*)&wt_lds[ra * 72 + cc + 8] = *(const ushort8*)(wrow + j0 + cc + 8);
        __syncthreads();
        #pragma unroll
        for (int k0 = 0; k0 < 64; k0 += 32) {
            bf16x8 a = *(const bf16x8*)&p_lds[(16 * wv + r) * 72 + k0 + q * 8];
            #pragma unroll
            for (int f = 0; f < 4; ++f) {
                bf16x8 bb = *(const bf16x8*)&wt_lds[(16 * f + r) * 72 + k0 + q * 8];
                acc[f] = __builtin_amdgcn_mfma_f32_16x16x32_bf16(a, bb, acc[f], 0, 0, 0);
            }
        }
        __syncthreads();
    }

    // epilogue: raw partial write (elu + /Z happen in k_wh2)
    float* xp = x_part + (size_t)s * (B_ * N_) * 512;
    #pragma unroll
    for (int f = 0; f < 4; ++f) {
        #pragma unroll
        for (int rr = 0; rr < 4; ++rr) {
            int i = i0 + 16 * wv + 4 * q + rr;
            xp[((size_t)(b * N_ + i)) * 512 + h * 64 + 16 * f + r] = acc[f][rr];
        }
    }
}

// ---------- K4: x = elu(sum_s part / Z); wh2 = x @ W_last; fused g1/g2 ----------
__global__ __launch_bounds__(256) void k_wh2(
    const float* __restrict__ x_part,
    const float* __restrict__ z1,
    const float* __restrict__ W_last,  // [512][2] f32
    const float* __restrict__ a_last,  // [4] f32
    float* __restrict__ wh2, float* __restrict__ g1, float* __restrict__ g2,
    int S)
{
    int idx = blockIdx.x * 4 + (threadIdx.x >> 6);  // b*N + n
    int lane = threadIdx.x & 63;
    int b = idx >> 11, n = idx & (N_ - 1);
    float a0 = 0.f, a1 = 0.f;
    #pragma unroll
    for (int it = 0; it < 8; ++it) {
        int k = it * 64 + lane;
        float xv = 0.f;
        for (int s = 0; s < S; ++s)
            xv += x_part[((size_t)s * (B_ * N_) + idx) * 512 + k];
        float zv = z1[((size_t)(b * H_) + (k >> 6)) * N_ + n];
        float x = xv / zv;
        x = x > 0.f ? x : expm1f(x);
        float2v wl = *(const float2v*)(W_last + k * 2);
        a0 += x * wl[0];
        a1 += x * wl[1];
    }
    #pragma unroll
    for (int s = 1; s < 64; s <<= 1) {
        a0 += __shfl_xor(a0, s, 64);
        a1 += __shfl_xor(a1, s, 64);
    }
    if (lane == 0) {
        wh2[idx * 2] = a0; wh2[idx * 2 + 1] = a1;
        g1[idx] = a0 * a_last[0] + a1 * a_last[1];
        g2[idx] = a0 * a_last[2] + a1 * a_last[3];
    }
}

// ---------- K5: final attention + elu, two-pass register version ----------
__global__ __launch_bounds__(256) void k_out(
    const float* __restrict__ adj,
    const float* __restrict__ wh2,
    const float* __restrict__ g1, const float* __restrict__ g2,
    float* __restrict__ out)
{
    int idx = blockIdx.x * 4 + (threadIdx.x >> 6); // b*N + i
    int lane = threadIdx.x & 63;
    int b = idx >> 11;
    float gi = g1[idx];
    const float* arow = adj + (size_t)idx * N_;
    const float* g2b = g2 + (size_t)b * N_;
    const float* wh2b = wh2 + (size_t)b * N_ * 2;

    float ep[32];
    float M = NEGBIG;
    #pragma unroll
    for (int it = 0; it < 8; ++it) {
        int j = it * 256 + lane * 4;
        float4v a4 = *(const float4v*)(arow + j);
        float4v s4 = *(const float4v*)(g2b + j);
        #pragma unroll
        for (int e = 0; e < 4; ++e) {
            float l = leakyf(gi + s4[e]);
            float v = (a4[e] != 0.f) ? l : NEGBIG;
            ep[it * 4 + e] = v;
            M = fmaxf(M, v);
        }
    }
    #pragma unroll
    for (int s = 1; s < 64; s <<= 1) M = fmaxf(M, __shfl_xor(M, s, 64));

    float Z = 0.f, A0 = 0.f, A1 = 0.f;
    #pragma unroll
    for (int it = 0; it < 8; ++it) {
        int j = it * 256 + lane * 4;
        float4v wA = *(const float4v*)(wh2b + 2 * j);
        float4v wB = *(const float4v*)(wh2b + 2 * j + 4);
        #pragma unroll
        for (int e = 0; e < 4; ++e) {
            float p = __expf(ep[it * 4 + e] - M);
            Z += p;
            float w0 = (e < 2) ? wA[2 * e] : wB[2 * (e - 2)];
            float w1 = (e < 2) ? wA[2 * e + 1] : wB[2 * (e - 2) + 1];
            A0 += p * w0;
            A1 += p * w1;
        }
    }
    #pragma unroll
    for (int s = 1; s < 64; s <<= 1) {
        Z += __shfl_xor(Z, s, 64);
        A0 += __shfl_xor(A0, s, 64);
        A1 += __shfl_xor(A1, s, 64);
    }
    if (lane == 0) {
        float o0 = A0 / Z, o1 = A1 / Z;
        o0 = o0 > 0.f ? o0 : expm1f(o0);
        o1 = o1 > 0.f ? o1 : expm1f(o1);
        float2v ov; ov[0] = o0; ov[1] = o1;
        *(float2v*)(out + idx * 2) = ov;
    }
}

extern "C" void kernel_launch(void* const* d_in, const int* in_sizes, int n_in,
                              void* d_out, int out_size, void* d_ws, size_t ws_size,
                              hipStream_t stream) {
    const float* fea    = (const float*)d_in[0];
    const float* adj    = (const float*)d_in[1];
    const float* W_att  = (const float*)d_in[2];
    const float* a_att  = (const float*)d_in[3];
    const float* W_last = (const float*)d_in[4];
    const float* a_last = (const float*)d_in[5];

    char* ws = (char*)d_ws;
    // layout (bytes)
    float* e1  = (float*)(ws + 0);                            // 131,072
    float* e2  = (float*)(ws + 131072);                       // 131,072
    float* m1  = (float*)(ws + 262144);                       // 131,072
    float* z1  = (float*)(ws + 393216);                       // 131,072
    float* wh2 = (float*)(ws + 524288);                       // 32,768
    float* g1  = (float*)(ws + 557056);                       // 16,384
    float* g2  = (float*)(ws + 573440);                       // 16,384
    unsigned short* WT  = (unsigned short*)(ws + 589824);     // 262,144
    unsigned short* whT = (unsigned short*)(ws + 851968);     // 4,194,304
    float* x_part = (float*)(ws + 5046272);                   // S * 8,388,608

    const size_t XPART = 8388608ULL;
    int S = (ws_size >= 5046272ULL + 4 * XPART) ? 4
          : (ws_size >= 5046272ULL + 2 * XPART) ? 2 : 1;
    int jPer = N_ / S;

    hipLaunchKernelGGL(k_transpose_w, dim3(H_), dim3(256), 0, stream, W_att, WT);
    hipLaunchKernelGGL(k_wh, dim3(B_ * H_ * (N_ / 64)), dim3(256), 0, stream,
                       fea, WT, a_att, whT, e1, e2);
    hipLaunchKernelGGL(k_stats1, dim3(B_ * H_ * N_ / 4), dim3(256), 0, stream,
                       adj, e1, e2, m1, z1);
    hipLaunchKernelGGL(k_pv1, dim3(S, N_ / 64, B_ * H_), dim3(256), 0, stream,
                       adj, whT, e1, e2, m1, x_part, jPer);
    hipLaunchKernelGGL(k_wh2, dim3(B_ * N_ / 4), dim3(256), 0, stream,
                       x_part, z1, W_last, a_last, wh2, g1, g2, S);
    hipLaunchKernelGGL(k_out, dim3(B_ * N_ / 4), dim3(256), 0, stream,
                       adj, wh2, g1, g2, (float*)d_out);
}

// Round 4
// 104.623 us; speedup vs baseline: 1.4807x; 1.1683x over previous
//
#include <hip/hip_runtime.h>
#include <hip/hip_bf16.h>
#include <cstdint>
#include <cstddef>

#define B_ 2
#define N_ 2048
#define D_ 256
#define H_ 8
#define HID_ 64
#define EN_ 2
#define ALPHA 0.2f
#define NEGBIG (-3.0e38f)
#define LOG2E 1.4426950408889634f

typedef __bf16 bf16x8 __attribute__((ext_vector_type(8)));
typedef float f32x4 __attribute__((ext_vector_type(4)));
typedef unsigned short ushort8 __attribute__((ext_vector_type(8)));
typedef float float4v __attribute__((ext_vector_type(4)));
typedef float float2v __attribute__((ext_vector_type(2)));

__device__ __forceinline__ unsigned short f2bf(float f) {
    unsigned int u = __builtin_bit_cast(unsigned int, f);
    unsigned int r = u + 0x7FFFu + ((u >> 16) & 1u);  // RNE
    return (unsigned short)(r >> 16);
}
__device__ __forceinline__ float leakyf(float x) { return fmaxf(x, ALPHA * x); }

// load 8 consecutive f32, convert to 8 bf16
__device__ __forceinline__ ushort8 cvt8(const float* __restrict__ p) {
    float4v x0 = *(const float4v*)p;
    float4v x1 = *(const float4v*)(p + 4);
    ushort8 r;
    #pragma unroll
    for (int e = 0; e < 4; ++e) { r[e] = f2bf(x0[e]); r[e + 4] = f2bf(x1[e]); }
    return r;
}

// ---------- K0: transpose W_att[h][d][o] f32 -> WT[h][o][d] bf16 (tiny) ----------
__global__ void k_transpose_w(const float* __restrict__ W,
                              unsigned short* __restrict__ WT) {
    int h = blockIdx.x;
    const float* Wh = W + (size_t)h * D_ * HID_;
    unsigned short* WTh = WT + (size_t)h * HID_ * D_;
    for (int idx = threadIdx.x; idx < D_ * HID_; idx += blockDim.x) {
        int d = idx / HID_, o = idx % HID_;
        WTh[o * D_ + d] = f2bf(Wh[idx]);
    }
}

// ---------- K1: wh = fea @ W_att (per b,h), fused e1/e2 (scaled by LOG2E) ----------
__global__ __launch_bounds__(256) void k_wh(
    const float* __restrict__ fea,            // [B][N][D] f32
    const unsigned short* __restrict__ WT,    // [H][64][256] bf16
    const float* __restrict__ a_att,          // [H][128] f32
    unsigned short* __restrict__ whT,         // [B][H][64][N] bf16
    float* __restrict__ e1, float* __restrict__ e2)
{
    int bid = blockIdx.x;
    int i0 = (bid & 31) << 6;
    int h  = (bid >> 5) & 7;
    int b  = bid >> 8;

    __shared__ __align__(16) union SmemA {
        struct { unsigned short fa[64 * 72]; unsigned short wt[64 * 72]; } s;
        float tr[64 * 65];
    } u;

    int t = threadIdx.x;
    int lane = t & 63;
    int wv = t >> 6;          // wave id 0..3
    int r = lane & 15, q = lane >> 4;
    int ra = t >> 2;          // staging row 0..63
    int cc = (t & 3) * 16;    // staging col chunk

    f32x4 acc[4] = {};

    const float* fearow = fea + ((size_t)(b * N_ + i0 + ra)) * D_;
    const unsigned short* wtrow = WT + ((size_t)(h * 64 + ra)) * D_;

    for (int d0 = 0; d0 < D_; d0 += 64) {
        *(ushort8*)&u.s.fa[ra * 72 + cc]     = cvt8(fearow + d0 + cc);
        *(ushort8*)&u.s.fa[ra * 72 + cc + 8] = cvt8(fearow + d0 + cc + 8);
        *(ushort8*)&u.s.wt[ra * 72 + cc]     = *(const ushort8*)(wtrow + d0 + cc);
        *(ushort8*)&u.s.wt[ra * 72 + cc + 8] = *(const ushort8*)(wtrow + d0 + cc + 8);
        __syncthreads();
        #pragma unroll
        for (int k0 = 0; k0 < 64; k0 += 32) {
            bf16x8 a = *(const bf16x8*)&u.s.fa[(16 * wv + r) * 72 + k0 + q * 8];
            #pragma unroll
            for (int f = 0; f < 4; ++f) {
                bf16x8 bb = *(const bf16x8*)&u.s.wt[(16 * f + r) * 72 + k0 + q * 8];
                acc[f] = __builtin_amdgcn_mfma_f32_16x16x32_bf16(a, bb, acc[f], 0, 0, 0);
            }
        }
        __syncthreads();
    }

    // e1/e2 epilogue (scaled by LOG2E for exp2-domain softmax downstream)
    float a1v[4], a2v[4];
    #pragma unroll
    for (int f = 0; f < 4; ++f) {
        a1v[f] = a_att[h * 128 + 16 * f + r];
        a2v[f] = a_att[h * 128 + 64 + 16 * f + r];
    }
    #pragma unroll
    for (int rr = 0; rr < 4; ++rr) {
        float s1 = 0.f, s2 = 0.f;
        #pragma unroll
        for (int f = 0; f < 4; ++f) { s1 += acc[f][rr] * a1v[f]; s2 += acc[f][rr] * a2v[f]; }
        #pragma unroll
        for (int m = 1; m < 16; m <<= 1) {
            s1 += __shfl_xor(s1, m, 64);
            s2 += __shfl_xor(s2, m, 64);
        }
        if (r == 0) {
            int i = i0 + 16 * wv + 4 * q + rr;
            size_t idx = ((size_t)(b * H_ + h)) * N_ + i;
            e1[idx] = s1 * LOG2E; e2[idx] = s2 * LOG2E;
        }
    }

    // transpose wh tile -> whT (via LDS)
    #pragma unroll
    for (int f = 0; f < 4; ++f)
        #pragma unroll
        for (int rr = 0; rr < 4; ++rr)
            u.tr[(16 * f + r) * 65 + 16 * wv + 4 * q + rr] = acc[f][rr];
    __syncthreads();
    {
        int o = t >> 2;
        int ch = (t & 3) * 16;
        unsigned short tmp[16];
        #pragma unroll
        for (int e = 0; e < 16; ++e) tmp[e] = f2bf(u.tr[o * 65 + ch + e]);
        ushort8* dst = (ushort8*)(whT + (((size_t)(b * H_ + h) * 64 + o)) * N_ + i0 + ch);
        dst[0] = *(ushort8*)&tmp[0];
        dst[1] = *(ushort8*)&tmp[8];
    }
}

// ---------- K2: maxE2[bh] = max_j e2[bh][j] (tiny) ----------
__global__ __launch_bounds__(256) void k_maxe2(const float* __restrict__ e2,
                                               float* __restrict__ mx) {
    int bh = blockIdx.x;
    int t = threadIdx.x;
    const float* row = e2 + (size_t)bh * N_;
    float M = NEGBIG;
    #pragma unroll
    for (int it = 0; it < N_ / 256; ++it) M = fmaxf(M, row[it * 256 + t]);
    #pragma unroll
    for (int s = 1; s < 64; s <<= 1) M = fmaxf(M, __shfl_xor(M, s, 64));
    __shared__ float red[4];
    if ((t & 63) == 0) red[t >> 6] = M;
    __syncthreads();
    if (t == 0) mx[bh] = fmaxf(fmaxf(red[0], red[1]), fmaxf(red[2], red[3]));
}

// ---------- K3: x_part[s] = P_chunk @ wh (raw); Z via ones-MFMA ----------
template<int JPER>
__global__ __launch_bounds__(256) void k_pv1(
    const float* __restrict__ adj,
    const unsigned short* __restrict__ whT,   // [B][H][64][N] bf16
    const float* __restrict__ e1, const float* __restrict__ e2,
    const float* __restrict__ maxE2,
    float* __restrict__ x_part,               // [S][B][N][512] f32
    float* __restrict__ zPart)                // [S][16][N] f32
{
    constexpr int NT = JPER / 64;
    int s  = blockIdx.x;
    int i0 = blockIdx.y << 6;
    int bh = blockIdx.z;                      // b*H + h
    int h = bh & 7, b = bh >> 3;
    int jBeg = s * JPER;

    __shared__ __align__(16) unsigned short p_lds[64 * 72];
    __shared__ __align__(16) unsigned short wt_lds[64 * 72];

    int t = threadIdx.x;
    int lane = t & 63;
    int wv = t >> 6;
    int r = lane & 15, q = lane >> 4;
    int ra = t >> 2;
    int cc = (t & 3) * 16;

    size_t rowIdx = ((size_t)bh) * N_ + i0 + ra;
    float eRow = e1[rowIdx];
    float m = leakyf(eRow + maxE2[bh]);       // upper bound >= masked row max
    float eRm = eRow - m;
    float eR2 = ALPHA * eRow - m;
    const float* e2row = e2 + ((size_t)bh) * N_;
    const float* abase = adj + ((size_t)(b * N_ + i0 + ra)) * N_ + jBeg + cc;
    const unsigned short* wbase = whT + (((size_t)bh) * 64 + ra) * N_ + jBeg + cc;

    bf16x8 ones;
    #pragma unroll
    for (int e = 0; e < 8; ++e) ones[e] = (__bf16)1.0f;

    f32x4 acc[4] = {};
    f32x4 accz = {};

    // prefetch tile 0 adj into regs
    float4v avN[4];
    #pragma unroll
    for (int u4 = 0; u4 < 4; ++u4) avN[u4] = *(const float4v*)(abase + u4 * 4);

    #pragma unroll 1
    for (int t8 = 0; t8 < NT; ++t8) {
        float4v ev[4];
        #pragma unroll
        for (int u4 = 0; u4 < 4; ++u4)
            ev[u4] = *(const float4v*)(e2row + jBeg + t8 * 64 + cc + u4 * 4);

        // P-gen in exp2 domain: 2^(leaky(e1+e2)-m) * adj
        float pf[16];
        #pragma unroll
        for (int e = 0; e < 16; ++e) {
            float e2v = ev[e >> 2][e & 3];
            float t0 = eRm + e2v;
            float t1 = __builtin_fmaf(ALPHA, e2v, eR2);
            float p = __builtin_amdgcn_exp2f(fmaxf(t0, t1));
            pf[e] = p * avN[e >> 2][e & 3];
        }
        // issue next tile's adj loads now (hide HBM latency under MFMA)
        if (t8 + 1 < NT) {
            #pragma unroll
            for (int u4 = 0; u4 < 4; ++u4)
                avN[u4] = *(const float4v*)(abase + (t8 + 1) * 64 + u4 * 4);
        }
        bf16x8 pv0, pv1;
        #pragma unroll
        for (int e = 0; e < 8; ++e) { pv0[e] = (__bf16)pf[e]; pv1[e] = (__bf16)pf[e + 8]; }
        *(bf16x8*)&p_lds[ra * 72 + cc]     = pv0;
        *(bf16x8*)&p_lds[ra * 72 + cc + 8] = pv1;
        *(ushort8*)&wt_lds[ra * 72 + cc]     = *(const ushort8*)(wbase + t8 * 64);
        *(ushort8*)&wt_lds[ra * 72 + cc + 8] = *(const ushort8*)(wbase + t8 * 64 + 8);
        __syncthreads();
        #pragma unroll
        for (int k0 = 0; k0 < 64; k0 += 32) {
            bf16x8 a = *(const bf16x8*)&p_lds[(16 * wv + r) * 72 + k0 + q * 8];
            accz = __builtin_amdgcn_mfma_f32_16x16x32_bf16(a, ones, accz, 0, 0, 0);
            #pragma unroll
            for (int f = 0; f < 4; ++f) {
                bf16x8 bb = *(const bf16x8*)&wt_lds[(16 * f + r) * 72 + k0 + q * 8];
                acc[f] = __builtin_amdgcn_mfma_f32_16x16x32_bf16(a, bb, acc[f], 0, 0, 0);
            }
        }
        __syncthreads();
    }

    // epilogue: raw partial write (elu + /Z happen in k_wh2)
    float* xp = x_part + (size_t)s * (B_ * N_) * 512;
    #pragma unroll
    for (int f = 0; f < 4; ++f) {
        #pragma unroll
        for (int rr = 0; rr < 4; ++rr) {
            int i = i0 + 16 * wv + 4 * q + rr;
            xp[((size_t)(b * N_ + i)) * 512 + h * 64 + 16 * f + r] = acc[f][rr];
        }
    }
    if (r == 0) {
        #pragma unroll
        for (int rr = 0; rr < 4; ++rr) {
            int i = i0 + 16 * wv + 4 * q + rr;
            zPart[((size_t)(s * 16 + bh)) * N_ + i] = accz[rr];
        }
    }
}

// ---------- K4: x = elu(sum_s part / Z); wh2 = x @ W_last; g1/g2 scaled ----------
__global__ __launch_bounds__(256) void k_wh2(
    const float* __restrict__ x_part,
    const float* __restrict__ zPart,
    const float* __restrict__ W_last,  // [512][2] f32
    const float* __restrict__ a_last,  // [4] f32
    float* __restrict__ wh2, float* __restrict__ g1, float* __restrict__ g2,
    int S)
{
    int idx = blockIdx.x * 4 + (threadIdx.x >> 6);  // b*N + n
    int lane = threadIdx.x & 63;
    int b = idx >> 11, n = idx & (N_ - 1);
    float a0 = 0.f, a1 = 0.f;
    #pragma unroll
    for (int it = 0; it < 8; ++it) {        // it == head index
        int k = it * 64 + lane;
        float xv = 0.f, zv = 0.f;
        for (int s = 0; s < S; ++s) {
            xv += x_part[((size_t)s * (B_ * N_) + idx) * 512 + k];
            zv += zPart[((size_t)(s * 16 + b * 8 + it)) * N_ + n];
        }
        float x = (zv > 0.f) ? xv / zv : 0.f;
        x = x > 0.f ? x : expm1f(x);
        float2v wl = *(const float2v*)(W_last + k * 2);
        a0 += x * wl[0];
        a1 += x * wl[1];
    }
    #pragma unroll
    for (int s = 1; s < 64; s <<= 1) {
        a0 += __shfl_xor(a0, s, 64);
        a1 += __shfl_xor(a1, s, 64);
    }
    if (lane == 0) {
        wh2[idx * 2] = a0; wh2[idx * 2 + 1] = a1;
        g1[idx] = (a0 * a_last[0] + a1 * a_last[1]) * LOG2E;
        g2[idx] = (a0 * a_last[2] + a1 * a_last[3]) * LOG2E;
    }
}

// ---------- K5: final attention + elu, two-pass register version (exp2) ----------
__global__ __launch_bounds__(256) void k_out(
    const float* __restrict__ adj,
    const float* __restrict__ wh2,
    const float* __restrict__ g1, const float* __restrict__ g2,
    float* __restrict__ out)
{
    int idx = blockIdx.x * 4 + (threadIdx.x >> 6); // b*N + i
    int lane = threadIdx.x & 63;
    int b = idx >> 11;
    float gi = g1[idx];
    const float* arow = adj + (size_t)idx * N_;
    const float* g2b = g2 + (size_t)b * N_;
    const float* wh2b = wh2 + (size_t)b * N_ * 2;

    float ep[32];
    float M = NEGBIG;
    #pragma unroll
    for (int it = 0; it < 8; ++it) {
        int j = it * 256 + lane * 4;
        float4v a4 = *(const float4v*)(arow + j);
        float4v s4 = *(const float4v*)(g2b + j);
        #pragma unroll
        for (int e = 0; e < 4; ++e) {
            float l = leakyf(gi + s4[e]);
            float v = (a4[e] != 0.f) ? l : NEGBIG;
            ep[it * 4 + e] = v;
            M = fmaxf(M, v);
        }
    }
    #pragma unroll
    for (int s = 1; s < 64; s <<= 1) M = fmaxf(M, __shfl_xor(M, s, 64));

    float Z = 0.f, A0 = 0.f, A1 = 0.f;
    #pragma unroll
    for (int it = 0; it < 8; ++it) {
        int j = it * 256 + lane * 4;
        float4v wA = *(const float4v*)(wh2b + 2 * j);
        float4v wB = *(const float4v*)(wh2b + 2 * j + 4);
        #pragma unroll
        for (int e = 0; e < 4; ++e) {
            float p = __builtin_amdgcn_exp2f(ep[it * 4 + e] - M);
            Z += p;
            float w0 = (e < 2) ? wA[2 * e] : wB[2 * (e - 2)];
            float w1 = (e < 2) ? wA[2 * e + 1] : wB[2 * (e - 2) + 1];
            A0 += p * w0;
            A1 += p * w1;
        }
    }
    #pragma unroll
    for (int s = 1; s < 64; s <<= 1) {
        Z += __shfl_xor(Z, s, 64);
        A0 += __shfl_xor(A0, s, 64);
        A1 += __shfl_xor(A1, s, 64);
    }
    if (lane == 0) {
        float o0 = A0 / Z, o1 = A1 / Z;
        o0 = o0 > 0.f ? o0 : expm1f(o0);
        o1 = o1 > 0.f ? o1 : expm1f(o1);
        float2v ov; ov[0] = o0; ov[1] = o1;
        *(float2v*)(out + idx * 2) = ov;
    }
}

extern "C" void kernel_launch(void* const* d_in, const int* in_sizes, int n_in,
                              void* d_out, int out_size, void* d_ws, size_t ws_size,
                              hipStream_t stream) {
    const float* fea    = (const float*)d_in[0];
    const float* adj    = (const float*)d_in[1];
    const float* W_att  = (const float*)d_in[2];
    const float* a_att  = (const float*)d_in[3];
    const float* W_last = (const float*)d_in[4];
    const float* a_last = (const float*)d_in[5];

    char* ws = (char*)d_ws;
    // layout (bytes)
    float* e1  = (float*)(ws + 0);                            // 131,072
    float* e2  = (float*)(ws + 131072);                       // 131,072
    float* mxE = (float*)(ws + 262144);                       // 256 (pad)
    float* wh2 = (float*)(ws + 262400);                       // 32,768
    float* g1  = (float*)(ws + 295168);                       // 16,384
    float* g2  = (float*)(ws + 311552);                       // 16,384
    unsigned short* WT  = (unsigned short*)(ws + 327936);     // 262,144
    unsigned short* whT = (unsigned short*)(ws + 590080);     // 4,194,304
    float* zPart = (float*)(ws + 4784384);                    // 524,288 (S<=4)
    float* x_part = (float*)(ws + 5308672);                   // S * 8,388,608

    const size_t BASE = 5308672ULL, XPART = 8388608ULL;
    int S = (ws_size >= BASE + 4 * XPART) ? 4
          : (ws_size >= BASE + 2 * XPART) ? 2 : 1;

    k_transpose_w<<<dim3(H_), dim3(256), 0, stream>>>(W_att, WT);
    k_wh<<<dim3(B_ * H_ * (N_ / 64)), dim3(256), 0, stream>>>(
        fea, WT, a_att, whT, e1, e2);
    k_maxe2<<<dim3(B_ * H_), dim3(256), 0, stream>>>(e2, mxE);
    if (S == 4)
        k_pv1<512><<<dim3(4, N_ / 64, B_ * H_), dim3(256), 0, stream>>>(
            adj, whT, e1, e2, mxE, x_part, zPart);
    else if (S == 2)
        k_pv1<1024><<<dim3(2, N_ / 64, B_ * H_), dim3(256), 0, stream>>>(
            adj, whT, e1, e2, mxE, x_part, zPart);
    else
        k_pv1<2048><<<dim3(1, N_ / 64, B_ * H_), dim3(256), 0, stream>>>(
            adj, whT, e1, e2, mxE, x_part, zPart);
    k_wh2<<<dim3(B_ * N_ / 4), dim3(256), 0, stream>>>(
        x_part, zPart, W_last, a_last, wh2, g1, g2, S);
    k_out<<<dim3(B_ * N_ / 4), dim3(256), 0, stream>>>(
        adj, wh2, g1, g2, (float*)d_out);
}

// Round 5
// 104.350 us; speedup vs baseline: 1.4846x; 1.0026x over previous
//
#include <hip/hip_runtime.h>
#include <hip/hip_bf16.h>
#include <cstdint>
#include <cstddef>

#define B_ 2
#define N_ 2048
#define D_ 256
#define H_ 8
#define HID_ 64
#define EN_ 2
#define ALPHA 0.2f
#define NEGBIG (-3.0e38f)
#define LOG2E 1.4426950408889634f

typedef __bf16 bf16x8 __attribute__((ext_vector_type(8)));
typedef float f32x4 __attribute__((ext_vector_type(4)));
typedef unsigned short ushort8 __attribute__((ext_vector_type(8)));
typedef float float4v __attribute__((ext_vector_type(4)));
typedef float float2v __attribute__((ext_vector_type(2)));

__device__ __forceinline__ unsigned short f2bf(float f) {
    unsigned int u = __builtin_bit_cast(unsigned int, f);
    unsigned int r = u + 0x7FFFu + ((u >> 16) & 1u);  // RNE
    return (unsigned short)(r >> 16);
}
__device__ __forceinline__ float leakyf(float x) { return fmaxf(x, ALPHA * x); }

// load 8 consecutive f32, convert to 8 bf16
__device__ __forceinline__ ushort8 cvt8(const float* __restrict__ p) {
    float4v x0 = *(const float4v*)p;
    float4v x1 = *(const float4v*)(p + 4);
    ushort8 r;
    #pragma unroll
    for (int e = 0; e < 4; ++e) { r[e] = f2bf(x0[e]); r[e + 4] = f2bf(x1[e]); }
    return r;
}

// ---------- K0: transpose W_att[h][d][o] f32 -> WT[h][o][d] bf16 (tiny) ----------
__global__ void k_transpose_w(const float* __restrict__ W,
                              unsigned short* __restrict__ WT) {
    int h = blockIdx.x;
    const float* Wh = W + (size_t)h * D_ * HID_;
    unsigned short* WTh = WT + (size_t)h * HID_ * D_;
    for (int idx = threadIdx.x; idx < D_ * HID_; idx += blockDim.x) {
        int d = idx / HID_, o = idx % HID_;
        WTh[o * D_ + d] = f2bf(Wh[idx]);
    }
}

// ---------- K1: wh = fea @ W_att (per b,h), fused e1/e2 (scaled by LOG2E) ----------
__global__ __launch_bounds__(256) void k_wh(
    const float* __restrict__ fea,            // [B][N][D] f32
    const unsigned short* __restrict__ WT,    // [H][64][256] bf16
    const float* __restrict__ a_att,          // [H][128] f32
    unsigned short* __restrict__ whT,         // [B][H][64][N] bf16
    float* __restrict__ e1, float* __restrict__ e2)
{
    int bid = blockIdx.x;
    int i0 = (bid & 31) << 6;
    int h  = (bid >> 5) & 7;
    int b  = bid >> 8;

    __shared__ __align__(16) union SmemA {
        struct { unsigned short fa[64 * 72]; unsigned short wt[64 * 72]; } s;
        float tr[64 * 65];
    } u;

    int t = threadIdx.x;
    int lane = t & 63;
    int wv = t >> 6;          // wave id 0..3
    int r = lane & 15, q = lane >> 4;
    int ra = t >> 2;          // staging row 0..63
    int cc = (t & 3) * 16;    // staging col chunk

    f32x4 acc[4] = {};

    const float* fearow = fea + ((size_t)(b * N_ + i0 + ra)) * D_;
    const unsigned short* wtrow = WT + ((size_t)(h * 64 + ra)) * D_;

    for (int d0 = 0; d0 < D_; d0 += 64) {
        *(ushort8*)&u.s.fa[ra * 72 + cc]     = cvt8(fearow + d0 + cc);
        *(ushort8*)&u.s.fa[ra * 72 + cc + 8] = cvt8(fearow + d0 + cc + 8);
        *(ushort8*)&u.s.wt[ra * 72 + cc]     = *(const ushort8*)(wtrow + d0 + cc);
        *(ushort8*)&u.s.wt[ra * 72 + cc + 8] = *(const ushort8*)(wtrow + d0 + cc + 8);
        __syncthreads();
        #pragma unroll
        for (int k0 = 0; k0 < 64; k0 += 32) {
            bf16x8 a = *(const bf16x8*)&u.s.fa[(16 * wv + r) * 72 + k0 + q * 8];
            #pragma unroll
            for (int f = 0; f < 4; ++f) {
                bf16x8 bb = *(const bf16x8*)&u.s.wt[(16 * f + r) * 72 + k0 + q * 8];
                acc[f] = __builtin_amdgcn_mfma_f32_16x16x32_bf16(a, bb, acc[f], 0, 0, 0);
            }
        }
        __syncthreads();
    }

    // e1/e2 epilogue (scaled by LOG2E for exp2-domain softmax downstream)
    float a1v[4], a2v[4];
    #pragma unroll
    for (int f = 0; f < 4; ++f) {
        a1v[f] = a_att[h * 128 + 16 * f + r];
        a2v[f] = a_att[h * 128 + 64 + 16 * f + r];
    }
    #pragma unroll
    for (int rr = 0; rr < 4; ++rr) {
        float s1 = 0.f, s2 = 0.f;
        #pragma unroll
        for (int f = 0; f < 4; ++f) { s1 += acc[f][rr] * a1v[f]; s2 += acc[f][rr] * a2v[f]; }
        #pragma unroll
        for (int m = 1; m < 16; m <<= 1) {
            s1 += __shfl_xor(s1, m, 64);
            s2 += __shfl_xor(s2, m, 64);
        }
        if (r == 0) {
            int i = i0 + 16 * wv + 4 * q + rr;
            size_t idx = ((size_t)(b * H_ + h)) * N_ + i;
            e1[idx] = s1 * LOG2E; e2[idx] = s2 * LOG2E;
        }
    }

    // transpose wh tile -> whT (via LDS)
    #pragma unroll
    for (int f = 0; f < 4; ++f)
        #pragma unroll
        for (int rr = 0; rr < 4; ++rr)
            u.tr[(16 * f + r) * 65 + 16 * wv + 4 * q + rr] = acc[f][rr];
    __syncthreads();
    {
        int o = t >> 2;
        int ch = (t & 3) * 16;
        unsigned short tmp[16];
        #pragma unroll
        for (int e = 0; e < 16; ++e) tmp[e] = f2bf(u.tr[o * 65 + ch + e]);
        ushort8* dst = (ushort8*)(whT + (((size_t)(b * H_ + h) * 64 + o)) * N_ + i0 + ch);
        dst[0] = *(ushort8*)&tmp[0];
        dst[1] = *(ushort8*)&tmp[8];
    }
}

// ---------- K2: maxE2[bh] = max_j e2[bh][j] (tiny) ----------
__global__ __launch_bounds__(256) void k_maxe2(const float* __restrict__ e2,
                                               float* __restrict__ mx) {
    int bh = blockIdx.x;
    int t = threadIdx.x;
    const float* row = e2 + (size_t)bh * N_;
    float M = NEGBIG;
    #pragma unroll
    for (int it = 0; it < N_ / 256; ++it) M = fmaxf(M, row[it * 256 + t]);
    #pragma unroll
    for (int s = 1; s < 64; s <<= 1) M = fmaxf(M, __shfl_xor(M, s, 64));
    __shared__ float red[4];
    if ((t & 63) == 0) red[t >> 6] = M;
    __syncthreads();
    if (t == 0) mx[bh] = fmaxf(fmaxf(red[0], red[1]), fmaxf(red[2], red[3]));
}

// ---------- K3: x_part[s] = P_chunk @ wh; P generated as register A-frags ----------
// 8 waves x 16 rows = 128 i-rows per block. whT tile (64x64) in swizzled LDS.
template<int JPER>
__global__ __launch_bounds__(512, 4) void k_pv1(
    const float* __restrict__ adj,
    const unsigned short* __restrict__ whT,   // [B][H][64][N] bf16
    const float* __restrict__ e1g, const float* __restrict__ e2g,
    const float* __restrict__ maxE2,
    float* __restrict__ x_part,               // [S][B][N][512] f32
    float* __restrict__ zPart)                // [S][16][N] f32
{
    constexpr int NT = JPER / 64;
    int s  = blockIdx.x;
    int i0 = blockIdx.y << 7;                 // 128 rows per block
    int bh = blockIdx.z;                      // b*H + h
    int h = bh & 7, b = bh >> 3;
    int jBeg = s * JPER;

    __shared__ __align__(16) unsigned short wt_lds[64 * 64];  // 8 KB, XOR-swizzled

    int t = threadIdx.x;
    int lane = t & 63;
    int wv = t >> 6;                          // 0..7
    int r = lane & 15, q = lane >> 4;

    int ir = i0 + 16 * wv + r;                // this lane's P row
    float eRow = e1g[(size_t)bh * N_ + ir];
    float m = leakyf(eRow + maxE2[bh]);       // upper bound >= masked row max
    float eRm = eRow - m;
    float eR2 = ALPHA * eRow - m;

    const float* e2p = e2g + (size_t)bh * N_ + jBeg;
    const float* ap  = adj + ((size_t)(b * N_ + ir)) * N_ + jBeg;
    // whT staging: thread t covers row o=t>>3, j-chunk (t&7)*8; dest swizzled
    const unsigned short* wsrc =
        whT + ((size_t)bh * 64 + (t >> 3)) * N_ + jBeg + (t & 7) * 8;
    unsigned short* wdst = &wt_lds[(t * 8) ^ (((t >> 3) & 7) << 3)];

    int swz = (r & 7) << 3;
    int koff0 = (8 * q) ^ swz;                // swizzled col offset, k-half 0
    int koff1 = (32 + 8 * q) ^ swz;           // k-half 1

    bf16x8 ones;
    #pragma unroll
    for (int e = 0; e < 8; ++e) ones[e] = (__bf16)1.0f;

    f32x4 acc[4] = {};
    f32x4 accz = {};

    #pragma unroll 1
    for (int t8 = 0; t8 < NT; ++t8) {
        // stage whT tile (16B/thread, swizzled dest)
        *(ushort8*)wdst = *(const ushort8*)(wsrc + t8 * 64);

        // P-gen straight into MFMA A-fragments (no LDS for P)
        const float* aj = ap + t8 * 64 + q * 8;
        const float* ej = e2p + t8 * 64 + q * 8;
        float4v a0 = *(const float4v*)(aj);
        float4v a1 = *(const float4v*)(aj + 4);
        float4v b0 = *(const float4v*)(aj + 32);
        float4v b1 = *(const float4v*)(aj + 36);
        float4v f0 = *(const float4v*)(ej);
        float4v f1 = *(const float4v*)(ej + 4);
        float4v g0 = *(const float4v*)(ej + 32);
        float4v g1 = *(const float4v*)(ej + 36);
        bf16x8 pa0, pa1;
        #pragma unroll
        for (int e = 0; e < 4; ++e) {
            float p;
            p = __builtin_amdgcn_exp2f(fmaxf(eRm + f0[e], __builtin_fmaf(ALPHA, f0[e], eR2)));
            pa0[e] = (__bf16)(p * a0[e]);
            p = __builtin_amdgcn_exp2f(fmaxf(eRm + f1[e], __builtin_fmaf(ALPHA, f1[e], eR2)));
            pa0[e + 4] = (__bf16)(p * a1[e]);
            p = __builtin_amdgcn_exp2f(fmaxf(eRm + g0[e], __builtin_fmaf(ALPHA, g0[e], eR2)));
            pa1[e] = (__bf16)(p * b0[e]);
            p = __builtin_amdgcn_exp2f(fmaxf(eRm + g1[e], __builtin_fmaf(ALPHA, g1[e], eR2)));
            pa1[e + 4] = (__bf16)(p * b1[e]);
        }

        __syncthreads();   // whT tile visible to all waves
        {
            bf16x8 bb;
            #pragma unroll
            for (int f = 0; f < 4; ++f) {
                bb = *(const bf16x8*)&wt_lds[f * 1024 + r * 64 + koff0];
                acc[f] = __builtin_amdgcn_mfma_f32_16x16x32_bf16(pa0, bb, acc[f], 0, 0, 0);
            }
            accz = __builtin_amdgcn_mfma_f32_16x16x32_bf16(pa0, ones, accz, 0, 0, 0);
            #pragma unroll
            for (int f = 0; f < 4; ++f) {
                bb = *(const bf16x8*)&wt_lds[f * 1024 + r * 64 + koff1];
                acc[f] = __builtin_amdgcn_mfma_f32_16x16x32_bf16(pa1, bb, acc[f], 0, 0, 0);
            }
            accz = __builtin_amdgcn_mfma_f32_16x16x32_bf16(pa1, ones, accz, 0, 0, 0);
        }
        __syncthreads();   // protect tile before next overwrite
    }

    // epilogue: raw partial write (elu + /Z happen in k_wh2)
    float* xp = x_part + ((size_t)s * (B_ * N_) + (size_t)b * N_) * 512 + h * 64;
    #pragma unroll
    for (int f = 0; f < 4; ++f) {
        #pragma unroll
        for (int rr = 0; rr < 4; ++rr) {
            int i = i0 + 16 * wv + 4 * q + rr;
            xp[(size_t)i * 512 + 16 * f + r] = acc[f][rr];
        }
    }
    if (r == 0) {
        #pragma unroll
        for (int rr = 0; rr < 4; ++rr) {
            int i = i0 + 16 * wv + 4 * q + rr;
            zPart[((size_t)(s * 16 + bh)) * N_ + i] = accz[rr];
        }
    }
}

// ---------- K4: x = elu(sum_s part / Z); wh2 = x @ W_last; g1/g2 scaled ----------
__global__ __launch_bounds__(256) void k_wh2(
    const float* __restrict__ x_part,
    const float* __restrict__ zPart,
    const float* __restrict__ W_last,  // [512][2] f32
    const float* __restrict__ a_last,  // [4] f32
    float* __restrict__ wh2, float* __restrict__ g1, float* __restrict__ g2,
    int S)
{
    int idx = blockIdx.x * 4 + (threadIdx.x >> 6);  // b*N + n
    int lane = threadIdx.x & 63;
    int b = idx >> 11, n = idx & (N_ - 1);
    float a0 = 0.f, a1 = 0.f;
    #pragma unroll
    for (int it = 0; it < 8; ++it) {        // it == head index
        int k = it * 64 + lane;
        float xv = 0.f, zv = 0.f;
        for (int s = 0; s < S; ++s) {
            xv += x_part[((size_t)s * (B_ * N_) + idx) * 512 + k];
            zv += zPart[((size_t)(s * 16 + b * 8 + it)) * N_ + n];
        }
        float x = (zv > 0.f) ? xv / zv : 0.f;
        x = x > 0.f ? x : expm1f(x);
        float2v wl = *(const float2v*)(W_last + k * 2);
        a0 += x * wl[0];
        a1 += x * wl[1];
    }
    #pragma unroll
    for (int s = 1; s < 64; s <<= 1) {
        a0 += __shfl_xor(a0, s, 64);
        a1 += __shfl_xor(a1, s, 64);
    }
    if (lane == 0) {
        wh2[idx * 2] = a0; wh2[idx * 2 + 1] = a1;
        g1[idx] = (a0 * a_last[0] + a1 * a_last[1]) * LOG2E;
        g2[idx] = (a0 * a_last[2] + a1 * a_last[3]) * LOG2E;
    }
}

// ---------- K5: final attention + elu, two-pass register version (exp2) ----------
__global__ __launch_bounds__(256) void k_out(
    const float* __restrict__ adj,
    const float* __restrict__ wh2,
    const float* __restrict__ g1, const float* __restrict__ g2,
    float* __restrict__ out)
{
    int idx = blockIdx.x * 4 + (threadIdx.x >> 6); // b*N + i
    int lane = threadIdx.x & 63;
    int b = idx >> 11;
    float gi = g1[idx];
    const float* arow = adj + (size_t)idx * N_;
    const float* g2b = g2 + (size_t)b * N_;
    const float* wh2b = wh2 + (size_t)b * N_ * 2;

    float ep[32];
    float M = NEGBIG;
    #pragma unroll
    for (int it = 0; it < 8; ++it) {
        int j = it * 256 + lane * 4;
        float4v a4 = *(const float4v*)(arow + j);
        float4v s4 = *(const float4v*)(g2b + j);
        #pragma unroll
        for (int e = 0; e < 4; ++e) {
            float l = leakyf(gi + s4[e]);
            float v = (a4[e] != 0.f) ? l : NEGBIG;
            ep[it * 4 + e] = v;
            M = fmaxf(M, v);
        }
    }
    #pragma unroll
    for (int s = 1; s < 64; s <<= 1) M = fmaxf(M, __shfl_xor(M, s, 64));

    float Z = 0.f, A0 = 0.f, A1 = 0.f;
    #pragma unroll
    for (int it = 0; it < 8; ++it) {
        int j = it * 256 + lane * 4;
        float4v wA = *(const float4v*)(wh2b + 2 * j);
        float4v wB = *(const float4v*)(wh2b + 2 * j + 4);
        #pragma unroll
        for (int e = 0; e < 4; ++e) {
            float p = __builtin_amdgcn_exp2f(ep[it * 4 + e] - M);
            Z += p;
            float w0 = (e < 2) ? wA[2 * e] : wB[2 * (e - 2)];
            float w1 = (e < 2) ? wA[2 * e + 1] : wB[2 * (e - 2) + 1];
            A0 += p * w0;
            A1 += p * w1;
        }
    }
    #pragma unroll
    for (int s = 1; s < 64; s <<= 1) {
        Z += __shfl_xor(Z, s, 64);
        A0 += __shfl_xor(A0, s, 64);
        A1 += __shfl_xor(A1, s, 64);
    }
    if (lane == 0) {
        float o0 = A0 / Z, o1 = A1 / Z;
        o0 = o0 > 0.f ? o0 : expm1f(o0);
        o1 = o1 > 0.f ? o1 : expm1f(o1);
        float2v ov; ov[0] = o0; ov[1] = o1;
        *(float2v*)(out + idx * 2) = ov;
    }
}

extern "C" void kernel_launch(void* const* d_in, const int* in_sizes, int n_in,
                              void* d_out, int out_size, void* d_ws, size_t ws_size,
                              hipStream_t stream) {
    const float* fea    = (const float*)d_in[0];
    const float* adj    = (const float*)d_in[1];
    const float* W_att  = (const float*)d_in[2];
    const float* a_att  = (const float*)d_in[3];
    const float* W_last = (const float*)d_in[4];
    const float* a_last = (const float*)d_in[5];

    char* ws = (char*)d_ws;
    // layout (bytes)
    float* e1  = (float*)(ws + 0);                            // 131,072
    float* e2  = (float*)(ws + 131072);                       // 131,072
    float* mxE = (float*)(ws + 262144);                       // 256 (pad)
    float* wh2 = (float*)(ws + 262400);                       // 32,768
    float* g1  = (float*)(ws + 295168);                       // 16,384
    float* g2  = (float*)(ws + 311552);                       // 16,384
    unsigned short* WT  = (unsigned short*)(ws + 327936);     // 262,144
    unsigned short* whT = (unsigned short*)(ws + 590080);     // 4,194,304
    float* zPart = (float*)(ws + 4784384);                    // 524,288 (S<=4)
    float* x_part = (float*)(ws + 5308672);                   // S * 8,388,608

    const size_t BASE = 5308672ULL, XPART = 8388608ULL;
    int S = (ws_size >= BASE + 4 * XPART) ? 4
          : (ws_size >= BASE + 2 * XPART) ? 2 : 1;

    k_transpose_w<<<dim3(H_), dim3(256), 0, stream>>>(W_att, WT);
    k_wh<<<dim3(B_ * H_ * (N_ / 64)), dim3(256), 0, stream>>>(
        fea, WT, a_att, whT, e1, e2);
    k_maxe2<<<dim3(B_ * H_), dim3(256), 0, stream>>>(e2, mxE);
    if (S == 4)
        k_pv1<512><<<dim3(4, N_ / 128, B_ * H_), dim3(512), 0, stream>>>(
            adj, whT, e1, e2, mxE, x_part, zPart);
    else if (S == 2)
        k_pv1<1024><<<dim3(2, N_ / 128, B_ * H_), dim3(512), 0, stream>>>(
            adj, whT, e1, e2, mxE, x_part, zPart);
    else
        k_pv1<2048><<<dim3(1, N_ / 128, B_ * H_), dim3(512), 0, stream>>>(
            adj, whT, e1, e2, mxE, x_part, zPart);
    k_wh2<<<dim3(B_ * N_ / 4), dim3(256), 0, stream>>>(
        x_part, zPart, W_last, a_last, wh2, g1, g2, S);
    k_out<<<dim3(B_ * N_ / 4), dim3(256), 0, stream>>>(
        adj, wh2, g1, g2, (float*)d_out);
}

// Round 6
// 98.779 us; speedup vs baseline: 1.5683x; 1.0564x over previous
//
#include <hip/hip_runtime.h>
#include <hip/hip_bf16.h>
#include <cstdint>
#include <cstddef>

#define B_ 2
#define N_ 2048
#define D_ 256
#define H_ 8
#define HID_ 64
#define EN_ 2
#define ALPHA 0.2f
#define NEGBIG (-3.0e38f)
#define LOG2E 1.4426950408889634f

typedef __bf16 bf16x8 __attribute__((ext_vector_type(8)));
typedef float f32x4 __attribute__((ext_vector_type(4)));
typedef unsigned short ushort8 __attribute__((ext_vector_type(8)));
typedef float float4v __attribute__((ext_vector_type(4)));
typedef float float2v __attribute__((ext_vector_type(2)));

__device__ __forceinline__ unsigned short f2bf(float f) {
    unsigned int u = __builtin_bit_cast(unsigned int, f);
    unsigned int r = u + 0x7FFFu + ((u >> 16) & 1u);  // RNE
    return (unsigned short)(r >> 16);
}
__device__ __forceinline__ float leakyf(float x) { return fmaxf(x, ALPHA * x); }

// load 8 consecutive f32, convert to 8 bf16
__device__ __forceinline__ ushort8 cvt8(const float* __restrict__ p) {
    float4v x0 = *(const float4v*)p;
    float4v x1 = *(const float4v*)(p + 4);
    ushort8 r;
    #pragma unroll
    for (int e = 0; e < 4; ++e) { r[e] = f2bf(x0[e]); r[e + 4] = f2bf(x1[e]); }
    return r;
}

// ---------- K0: transpose W_att[h][d][o] f32 -> WT[h][o][d] bf16 (tiny) ----------
__global__ void k_transpose_w(const float* __restrict__ W,
                              unsigned short* __restrict__ WT) {
    int h = blockIdx.x;
    const float* Wh = W + (size_t)h * D_ * HID_;
    unsigned short* WTh = WT + (size_t)h * HID_ * D_;
    for (int idx = threadIdx.x; idx < D_ * HID_; idx += blockDim.x) {
        int d = idx / HID_, o = idx % HID_;
        WTh[o * D_ + d] = f2bf(Wh[idx]);
    }
}

// ---------- K1: wh = fea @ W_att (per b,h), fused e1/e2 (scaled by LOG2E) ----------
__global__ __launch_bounds__(256) void k_wh(
    const float* __restrict__ fea,            // [B][N][D] f32
    const unsigned short* __restrict__ WT,    // [H][64][256] bf16
    const float* __restrict__ a_att,          // [H][128] f32
    unsigned short* __restrict__ whT,         // [B][H][64][N] bf16
    float* __restrict__ e1, float* __restrict__ e2)
{
    int bid = blockIdx.x;
    int i0 = (bid & 31) << 6;
    int h  = (bid >> 5) & 7;
    int b  = bid >> 8;

    __shared__ __align__(16) union SmemA {
        struct { unsigned short fa[64 * 72]; unsigned short wt[64 * 72]; } s;
        float tr[64 * 65];
    } u;

    int t = threadIdx.x;
    int lane = t & 63;
    int wv = t >> 6;          // wave id 0..3
    int r = lane & 15, q = lane >> 4;
    int ra = t >> 2;          // staging row 0..63
    int cc = (t & 3) * 16;    // staging col chunk

    f32x4 acc[4] = {};

    const float* fearow = fea + ((size_t)(b * N_ + i0 + ra)) * D_;
    const unsigned short* wtrow = WT + ((size_t)(h * 64 + ra)) * D_;

    for (int d0 = 0; d0 < D_; d0 += 64) {
        *(ushort8*)&u.s.fa[ra * 72 + cc]     = cvt8(fearow + d0 + cc);
        *(ushort8*)&u.s.fa[ra * 72 + cc + 8] = cvt8(fearow + d0 + cc + 8);
        *(ushort8*)&u.s.wt[ra * 72 + cc]     = *(const ushort8*)(wtrow + d0 + cc);
        *(ushort8*)&u.s.wt[ra * 72 + cc + 8] = *(const ushort8*)(wtrow + d0 + cc + 8);
        __syncthreads();
        #pragma unroll
        for (int k0 = 0; k0 < 64; k0 += 32) {
            bf16x8 a = *(const bf16x8*)&u.s.fa[(16 * wv + r) * 72 + k0 + q * 8];
            #pragma unroll
            for (int f = 0; f < 4; ++f) {
                bf16x8 bb = *(const bf16x8*)&u.s.wt[(16 * f + r) * 72 + k0 + q * 8];
                acc[f] = __builtin_amdgcn_mfma_f32_16x16x32_bf16(a, bb, acc[f], 0, 0, 0);
            }
        }
        __syncthreads();
    }

    // e1/e2 epilogue (scaled by LOG2E for exp2-domain softmax downstream)
    float a1v[4], a2v[4];
    #pragma unroll
    for (int f = 0; f < 4; ++f) {
        a1v[f] = a_att[h * 128 + 16 * f + r];
        a2v[f] = a_att[h * 128 + 64 + 16 * f + r];
    }
    #pragma unroll
    for (int rr = 0; rr < 4; ++rr) {
        float s1 = 0.f, s2 = 0.f;
        #pragma unroll
        for (int f = 0; f < 4; ++f) { s1 += acc[f][rr] * a1v[f]; s2 += acc[f][rr] * a2v[f]; }
        #pragma unroll
        for (int m = 1; m < 16; m <<= 1) {
            s1 += __shfl_xor(s1, m, 64);
            s2 += __shfl_xor(s2, m, 64);
        }
        if (r == 0) {
            int i = i0 + 16 * wv + 4 * q + rr;
            size_t idx = ((size_t)(b * H_ + h)) * N_ + i;
            e1[idx] = s1 * LOG2E; e2[idx] = s2 * LOG2E;
        }
    }

    // transpose wh tile -> whT (via LDS)
    #pragma unroll
    for (int f = 0; f < 4; ++f)
        #pragma unroll
        for (int rr = 0; rr < 4; ++rr)
            u.tr[(16 * f + r) * 65 + 16 * wv + 4 * q + rr] = acc[f][rr];
    __syncthreads();
    {
        int o = t >> 2;
        int ch = (t & 3) * 16;
        unsigned short tmp[16];
        #pragma unroll
        for (int e = 0; e < 16; ++e) tmp[e] = f2bf(u.tr[o * 65 + ch + e]);
        ushort8* dst = (ushort8*)(whT + (((size_t)(b * H_ + h) * 64 + o)) * N_ + i0 + ch);
        dst[0] = *(ushort8*)&tmp[0];
        dst[1] = *(ushort8*)&tmp[8];
    }
}

// ---------- K2: maxE2[bh] = max_j e2[bh][j] (tiny) ----------
__global__ __launch_bounds__(256) void k_maxe2(const float* __restrict__ e2,
                                               float* __restrict__ mx) {
    int bh = blockIdx.x;
    int t = threadIdx.x;
    const float* row = e2 + (size_t)bh * N_;
    float M = NEGBIG;
    #pragma unroll
    for (int it = 0; it < N_ / 256; ++it) M = fmaxf(M, row[it * 256 + t]);
    #pragma unroll
    for (int s = 1; s < 64; s <<= 1) M = fmaxf(M, __shfl_xor(M, s, 64));
    __shared__ float red[4];
    if ((t & 63) == 0) red[t >> 6] = M;
    __syncthreads();
    if (t == 0) mx[bh] = fmaxf(fmaxf(red[0], red[1]), fmaxf(red[2], red[3]));
}

// ---------- K3: x_part[s] = P_chunk @ wh; software-pipelined ----------
// 8 waves x 16 rows = 128 i-rows per block. whT tile double-buffered in LDS,
// one barrier per tile; adj prefetched 2 tiles deep; e2 slice staged in LDS.
template<int JPER>
__global__ __launch_bounds__(512, 4) void k_pv1(
    const float* __restrict__ adj,
    const unsigned short* __restrict__ whT,   // [B][H][64][N] bf16
    const float* __restrict__ e1g, const float* __restrict__ e2g,
    const float* __restrict__ maxE2,
    float* __restrict__ x_part,               // [S][B][N][512] f32
    float* __restrict__ zPart)                // [S][16][N] f32
{
    constexpr int NT = JPER / 64;
    int s  = blockIdx.x;
    int i0 = blockIdx.y << 7;                 // 128 rows per block
    int bh = blockIdx.z;                      // b*H + h
    int h = bh & 7, b = bh >> 3;
    int jBeg = s * JPER;

    __shared__ __align__(16) unsigned short wt_lds[2][64 * 64];  // 2x8 KB, swizzled
    __shared__ __align__(16) float e2s[2048];                    // e2 slice (<=8 KB)

    int t = threadIdx.x;
    int lane = t & 63;
    int wv = t >> 6;                          // 0..7
    int r = lane & 15, q = lane >> 4;

    int ir = i0 + 16 * wv + r;                // this lane's P row
    float eRow = e1g[(size_t)bh * N_ + ir];
    float m = leakyf(eRow + maxE2[bh]);       // upper bound >= masked row max
    float eRm = eRow - m;
    float eR2 = ALPHA * eRow - m;

    const float* e2p = e2g + (size_t)bh * N_ + jBeg;
    const float* ap  = adj + ((size_t)(b * N_ + ir)) * N_ + jBeg + q * 8;
    // whT staging: thread t covers row o=t>>3, j-chunk (t&7)*8; dest swizzled
    const unsigned short* wsrc =
        whT + ((size_t)bh * 64 + (t >> 3)) * N_ + jBeg + (t & 7) * 8;
    int woff = (t * 8) ^ (((t >> 3) & 7) << 3);

    int swz = (r & 7) << 3;
    int koff0 = (8 * q) ^ swz;                // swizzled col offset, k-half 0
    int koff1 = (32 + 8 * q) ^ swz;           // k-half 1

    bf16x8 ones;
    #pragma unroll
    for (int e = 0; e < 8; ++e) ones[e] = (__bf16)1.0f;

    f32x4 acc[4] = {};
    f32x4 accz = {};

    // register pipeline: adj 2 tiles deep, whT-stage regs 1 tile deep
    float4v aA[4], aB[4];
    ushort8 wA, wB;

#define LOADSET(A, W, tile) do {                                           \
        const float* ap_ = ap + (tile) * 64;                               \
        A[0] = *(const float4v*)(ap_);      A[1] = *(const float4v*)(ap_ + 4);  \
        A[2] = *(const float4v*)(ap_ + 32); A[3] = *(const float4v*)(ap_ + 36); \
        W = *(const ushort8*)(wsrc + (tile) * 64);                         \
    } while (0)

    // prologue: e2 slice -> LDS; tile0 -> set A (and buf0); tile1 -> set B
    for (int jj = t; jj < JPER; jj += 512) e2s[jj] = e2p[jj];
    LOADSET(aA, wA, 0);
    *(ushort8*)&wt_lds[0][woff] = wA;
    LOADSET(aB, wB, 1);
    __syncthreads();

    // P-gen: exp2(leaky-ish) * adj into MFMA A-fragments
    auto pgen = [&](const float4v* av, int t8, bf16x8& pa0, bf16x8& pa1) {
        const float* ejs = &e2s[t8 * 64 + q * 8];
        float4v f0 = *(const float4v*)(ejs);
        float4v f1 = *(const float4v*)(ejs + 4);
        float4v g0 = *(const float4v*)(ejs + 32);
        float4v g1 = *(const float4v*)(ejs + 36);
        #pragma unroll
        for (int e = 0; e < 4; ++e) {
            float p;
            p = __builtin_amdgcn_exp2f(fmaxf(eRm + f0[e], __builtin_fmaf(ALPHA, f0[e], eR2)));
            pa0[e] = (__bf16)(p * av[0][e]);
            p = __builtin_amdgcn_exp2f(fmaxf(eRm + f1[e], __builtin_fmaf(ALPHA, f1[e], eR2)));
            pa0[e + 4] = (__bf16)(p * av[1][e]);
            p = __builtin_amdgcn_exp2f(fmaxf(eRm + g0[e], __builtin_fmaf(ALPHA, g0[e], eR2)));
            pa1[e] = (__bf16)(p * av[2][e]);
            p = __builtin_amdgcn_exp2f(fmaxf(eRm + g1[e], __builtin_fmaf(ALPHA, g1[e], eR2)));
            pa1[e + 4] = (__bf16)(p * av[3][e]);
        }
    };

    #pragma unroll 2
    for (int t8 = 0; t8 < NT; ++t8) {
        const int cur = t8 & 1;
        bf16x8 pa0, pa1;
        if (cur == 0) pgen(aA, t8, pa0, pa1);
        else          pgen(aB, t8, pa0, pa1);

        // stage tile t8+1 into the other buffer (regs loaded one iter ago)
        if (t8 + 1 < NT) {
            if (cur == 0) *(ushort8*)&wt_lds[1][woff] = wB;
            else          *(ushort8*)&wt_lds[0][woff] = wA;
        }
        // issue loads for tile t8+2 into the just-freed register set
        if (t8 + 2 < NT) {
            if (cur == 0) LOADSET(aA, wA, t8 + 2);
            else          LOADSET(aB, wB, t8 + 2);
        }

        // MFMA on current buffer
        const unsigned short* Wb = wt_lds[cur];
        bf16x8 bb;
        #pragma unroll
        for (int f = 0; f < 4; ++f) {
            bb = *(const bf16x8*)&Wb[f * 1024 + r * 64 + koff0];
            acc[f] = __builtin_amdgcn_mfma_f32_16x16x32_bf16(pa0, bb, acc[f], 0, 0, 0);
        }
        accz = __builtin_amdgcn_mfma_f32_16x16x32_bf16(pa0, ones, accz, 0, 0, 0);
        #pragma unroll
        for (int f = 0; f < 4; ++f) {
            bb = *(const bf16x8*)&Wb[f * 1024 + r * 64 + koff1];
            acc[f] = __builtin_amdgcn_mfma_f32_16x16x32_bf16(pa1, bb, acc[f], 0, 0, 0);
        }
        accz = __builtin_amdgcn_mfma_f32_16x16x32_bf16(pa1, ones, accz, 0, 0, 0);
        __syncthreads();   // one barrier per tile (dbuf write/read separation)
    }
#undef LOADSET

    // epilogue: raw partial write (elu + /Z happen in k_wh2)
    float* xp = x_part + ((size_t)s * (B_ * N_) + (size_t)b * N_) * 512 + h * 64;
    #pragma unroll
    for (int f = 0; f < 4; ++f) {
        #pragma unroll
        for (int rr = 0; rr < 4; ++rr) {
            int i = i0 + 16 * wv + 4 * q + rr;
            xp[(size_t)i * 512 + 16 * f + r] = acc[f][rr];
        }
    }
    if (r == 0) {
        #pragma unroll
        for (int rr = 0; rr < 4; ++rr) {
            int i = i0 + 16 * wv + 4 * q + rr;
            zPart[((size_t)(s * 16 + bh)) * N_ + i] = accz[rr];
        }
    }
}

// ---------- K4: x = elu(sum_s part / Z); wh2 = x @ W_last; g1/g2 scaled ----------
__global__ __launch_bounds__(256) void k_wh2(
    const float* __restrict__ x_part,
    const float* __restrict__ zPart,
    const float* __restrict__ W_last,  // [512][2] f32
    const float* __restrict__ a_last,  // [4] f32
    float* __restrict__ wh2, float* __restrict__ g1, float* __restrict__ g2,
    int S)
{
    int idx = blockIdx.x * 4 + (threadIdx.x >> 6);  // b*N + n
    int lane = threadIdx.x & 63;
    int b = idx >> 11, n = idx & (N_ - 1);
    float a0 = 0.f, a1 = 0.f;
    #pragma unroll
    for (int it = 0; it < 8; ++it) {        // it == head index
        int k = it * 64 + lane;
        float xv = 0.f, zv = 0.f;
        for (int s = 0; s < S; ++s) {
            xv += x_part[((size_t)s * (B_ * N_) + idx) * 512 + k];
            zv += zPart[((size_t)(s * 16 + b * 8 + it)) * N_ + n];
        }
        float x = (zv > 0.f) ? xv / zv : 0.f;
        x = x > 0.f ? x : expm1f(x);
        float2v wl = *(const float2v*)(W_last + k * 2);
        a0 += x * wl[0];
        a1 += x * wl[1];
    }
    #pragma unroll
    for (int s = 1; s < 64; s <<= 1) {
        a0 += __shfl_xor(a0, s, 64);
        a1 += __shfl_xor(a1, s, 64);
    }
    if (lane == 0) {
        wh2[idx * 2] = a0; wh2[idx * 2 + 1] = a1;
        g1[idx] = (a0 * a_last[0] + a1 * a_last[1]) * LOG2E;
        g2[idx] = (a0 * a_last[2] + a1 * a_last[3]) * LOG2E;
    }
}

// ---------- K5: final attention + elu, two-pass register version (exp2) ----------
__global__ __launch_bounds__(256) void k_out(
    const float* __restrict__ adj,
    const float* __restrict__ wh2,
    const float* __restrict__ g1, const float* __restrict__ g2,
    float* __restrict__ out)
{
    int idx = blockIdx.x * 4 + (threadIdx.x >> 6); // b*N + i
    int lane = threadIdx.x & 63;
    int b = idx >> 11;
    float gi = g1[idx];
    const float* arow = adj + (size_t)idx * N_;
    const float* g2b = g2 + (size_t)b * N_;
    const float* wh2b = wh2 + (size_t)b * N_ * 2;

    float ep[32];
    float M = NEGBIG;
    #pragma unroll
    for (int it = 0; it < 8; ++it) {
        int j = it * 256 + lane * 4;
        float4v a4 = *(const float4v*)(arow + j);
        float4v s4 = *(const float4v*)(g2b + j);
        #pragma unroll
        for (int e = 0; e < 4; ++e) {
            float l = leakyf(gi + s4[e]);
            float v = (a4[e] != 0.f) ? l : NEGBIG;
            ep[it * 4 + e] = v;
            M = fmaxf(M, v);
        }
    }
    #pragma unroll
    for (int s = 1; s < 64; s <<= 1) M = fmaxf(M, __shfl_xor(M, s, 64));

    float Z = 0.f, A0 = 0.f, A1 = 0.f;
    #pragma unroll
    for (int it = 0; it < 8; ++it) {
        int j = it * 256 + lane * 4;
        float4v wA = *(const float4v*)(wh2b + 2 * j);
        float4v wB = *(const float4v*)(wh2b + 2 * j + 4);
        #pragma unroll
        for (int e = 0; e < 4; ++e) {
            float p = __builtin_amdgcn_exp2f(ep[it * 4 + e] - M);
            Z += p;
            float w0 = (e < 2) ? wA[2 * e] : wB[2 * (e - 2)];
            float w1 = (e < 2) ? wA[2 * e + 1] : wB[2 * (e - 2) + 1];
            A0 += p * w0;
            A1 += p * w1;
        }
    }
    #pragma unroll
    for (int s = 1; s < 64; s <<= 1) {
        Z += __shfl_xor(Z, s, 64);
        A0 += __shfl_xor(A0, s, 64);
        A1 += __shfl_xor(A1, s, 64);
    }
    if (lane == 0) {
        float o0 = A0 / Z, o1 = A1 / Z;
        o0 = o0 > 0.f ? o0 : expm1f(o0);
        o1 = o1 > 0.f ? o1 : expm1f(o1);
        float2v ov; ov[0] = o0; ov[1] = o1;
        *(float2v*)(out + idx * 2) = ov;
    }
}

extern "C" void kernel_launch(void* const* d_in, const int* in_sizes, int n_in,
                              void* d_out, int out_size, void* d_ws, size_t ws_size,
                              hipStream_t stream) {
    const float* fea    = (const float*)d_in[0];
    const float* adj    = (const float*)d_in[1];
    const float* W_att  = (const float*)d_in[2];
    const float* a_att  = (const float*)d_in[3];
    const float* W_last = (const float*)d_in[4];
    const float* a_last = (const float*)d_in[5];

    char* ws = (char*)d_ws;
    // layout (bytes)
    float* e1  = (float*)(ws + 0);                            // 131,072
    float* e2  = (float*)(ws + 131072);                       // 131,072
    float* mxE = (float*)(ws + 262144);                       // 256 (pad)
    float* wh2 = (float*)(ws + 262400);                       // 32,768
    float* g1  = (float*)(ws + 295168);                       // 16,384
    float* g2  = (float*)(ws + 311552);                       // 16,384
    unsigned short* WT  = (unsigned short*)(ws + 327936);     // 262,144
    unsigned short* whT = (unsigned short*)(ws + 590080);     // 4,194,304
    float* zPart = (float*)(ws + 4784384);                    // 524,288 (S<=4)
    float* x_part = (float*)(ws + 5308672);                   // S * 8,388,608

    const size_t BASE = 5308672ULL, XPART = 8388608ULL;
    int S = (ws_size >= BASE + 4 * XPART) ? 4
          : (ws_size >= BASE + 2 * XPART) ? 2 : 1;

    k_transpose_w<<<dim3(H_), dim3(256), 0, stream>>>(W_att, WT);
    k_wh<<<dim3(B_ * H_ * (N_ / 64)), dim3(256), 0, stream>>>(
        fea, WT, a_att, whT, e1, e2);
    k_maxe2<<<dim3(B_ * H_), dim3(256), 0, stream>>>(e2, mxE);
    if (S == 4)
        k_pv1<512><<<dim3(4, N_ / 128, B_ * H_), dim3(512), 0, stream>>>(
            adj, whT, e1, e2, mxE, x_part, zPart);
    else if (S == 2)
        k_pv1<1024><<<dim3(2, N_ / 128, B_ * H_), dim3(512), 0, stream>>>(
            adj, whT, e1, e2, mxE, x_part, zPart);
    else
        k_pv1<2048><<<dim3(1, N_ / 128, B_ * H_), dim3(512), 0, stream>>>(
            adj, whT, e1, e2, mxE, x_part, zPart);
    k_wh2<<<dim3(B_ * N_ / 4), dim3(256), 0, stream>>>(
        x_part, zPart, W_last, a_last, wh2, g1, g2, S);
    k_out<<<dim3(B_ * N_ / 4), dim3(256), 0, stream>>>(
        adj, wh2, g1, g2, (float*)d_out);
}